// Round 12
// baseline (379.738 us; speedup 1.0000x reference)
//
#include <hip/hip_runtime.h>
#include <hip/hip_bf16.h>

// Sparse MoE v12: gateup ported to the 8-phase-style 256-row template:
// BM=256 x 128-f(g+u), BK=64, 8 waves, 2-buffer LDS (128KB), 4 phases/K-tile,
// counted vmcnt(2), read-side XOR swizzle w/ pre-permuted gll16 sources.
// down/cvt/router unchanged from R11.
// T=4096 tokens, D=2048, E=8, F_E=1024, top-2, SCALE=4.

#define TOK 4096
#define DIM 2048
#define NE 8
#define FE 1024
#define SCALE_F 4.0f
#define BK 32

typedef __bf16 bf16x8 __attribute__((ext_vector_type(8)));
typedef __bf16 bf16x4 __attribute__((ext_vector_type(4)));
typedef float f32x4 __attribute__((ext_vector_type(4)));

__device__ __forceinline__ void gll16(const void* g, void* l) {
  __builtin_amdgcn_global_load_lds(
      (const __attribute__((address_space(1))) unsigned int*)g,
      (__attribute__((address_space(3))) unsigned int*)l, 16, 0, 0);
}

#define MFMA16(a, b, c) __builtin_amdgcn_mfma_f32_16x16x32_bf16((a), (b), (c), 0, 0, 0)
#define VMCNT2 asm volatile("s_waitcnt vmcnt(2)" ::: "memory")
#define VMCNT4 asm volatile("s_waitcnt vmcnt(4)" ::: "memory")
#define VMCNT0 asm volatile("s_waitcnt vmcnt(0)" ::: "memory")
#define LGKM0  asm volatile("s_waitcnt lgkmcnt(0)" ::: "memory")
#define SCHED0 __builtin_amdgcn_sched_barrier(0)
#define BAR    __builtin_amdgcn_s_barrier()

// ---------------- router ------------------------------------------------------
__global__ __launch_bounds__(256) void k_router(
    const float* __restrict__ x, const float* __restrict__ rw,
    const float* __restrict__ nw, __bf16* __restrict__ xbf,
    int* __restrict__ topi, float* __restrict__ topw, int* __restrict__ counts) {
  int t = blockIdx.x;
  int tid = threadIdx.x;
  const float* xr = x + (size_t)t * DIM;
  float ssq = 0.f;
  float pe[NE];
#pragma unroll
  for (int e = 0; e < NE; ++e) pe[e] = 0.f;

#pragma unroll
  for (int i = 0; i < 2; ++i) {
    int c4 = tid + i * 256;
    float4 v = ((const float4*)xr)[c4];
    int c = c4 * 4;
    bf16x4 b;
    b[0] = (__bf16)v.x; b[1] = (__bf16)v.y; b[2] = (__bf16)v.z; b[3] = (__bf16)v.w;
    *(bf16x4*)(xbf + (size_t)t * DIM + c) = b;
    float xs[4] = {v.x, v.y, v.z, v.w};
#pragma unroll
    for (int j = 0; j < 4; ++j) {
      float xc = xs[j];
      ssq += xc * xc;
      float m = nw[c + j] * xc;
#pragma unroll
      for (int e = 0; e < NE; ++e) pe[e] += m * rw[e * DIM + c + j];
    }
  }
#pragma unroll
  for (int off = 32; off > 0; off >>= 1) {
    ssq += __shfl_down(ssq, off);
#pragma unroll
    for (int e = 0; e < NE; ++e) pe[e] += __shfl_down(pe[e], off);
  }
  __shared__ float red[4][NE + 1];
  int wid = tid >> 6, lane = tid & 63;
  if (lane == 0) {
    red[wid][0] = ssq;
#pragma unroll
    for (int e = 0; e < NE; ++e) red[wid][1 + e] = pe[e];
  }
  __syncthreads();
  if (tid == 0) {
    float s = red[0][0] + red[1][0] + red[2][0] + red[3][0];
    float rs = rsqrtf(s / (float)DIM + 1e-6f);
    float l[NE];
#pragma unroll
    for (int e = 0; e < NE; ++e)
      l[e] = (red[0][1 + e] + red[1][1 + e] + red[2][1 + e] + red[3][1 + e]) * rs;
    int i1 = 0;
#pragma unroll
    for (int e = 1; e < NE; ++e) if (l[e] > l[i1]) i1 = e;
    int i2 = -1;
#pragma unroll
    for (int e = 0; e < NE; ++e) if (e != i1 && (i2 < 0 || l[e] > l[i2])) i2 = e;
    float e2 = __expf(l[i2] - l[i1]);
    float inv = 1.f / (1.f + e2);
    topi[2 * t] = i1; topi[2 * t + 1] = i2;
    topw[2 * t] = inv; topw[2 * t + 1] = e2 * inv;
    atomicAdd(&counts[i1], 1);
    atomicAdd(&counts[i2], 1);
  }
}

__global__ void k_prefix(const int* __restrict__ counts, int* __restrict__ offsets,
                         int* __restrict__ cursor) {
  if (threadIdx.x == 0 && blockIdx.x == 0) {
    int acc = 0;
    for (int e = 0; e < NE; ++e) {
      offsets[e] = acc;
      cursor[e] = acc;
      acc += counts[e];
    }
    offsets[NE] = acc;
  }
}

__global__ __launch_bounds__(256) void k_place(
    const int* __restrict__ topi, const float* __restrict__ topw,
    int* __restrict__ cursor, int* __restrict__ row_token,
    float* __restrict__ row_wt, int* __restrict__ invp) {
  int t = blockIdx.x * 256 + threadIdx.x;
  if (t >= TOK) return;
#pragma unroll
  for (int s = 0; s < 2; ++s) {
    int e = topi[2 * t + s];
    int pos = atomicAdd(&cursor[e], 1);
    row_token[pos] = t;
    row_wt[pos] = topw[2 * t + s] * SCALE_F;
    invp[2 * t + s] = pos;
  }
}

// ---- convert pass: [R][C] f32 -> [C][R] bf16; 256r x 32c tiles --------------
__global__ __launch_bounds__(256) void k_cvt2(
    const float* __restrict__ gw, const float* __restrict__ uw,
    const float* __restrict__ dwp, __bf16* __restrict__ gwt,
    __bf16* __restrict__ uwt, __bf16* __restrict__ dwt) {
  __shared__ float tile[32][257];
  int m = blockIdx.y;
  int which = m >> 3, e = m & 7;
  const float* src; __bf16* dst; int R, C;
  if (which == 0)      { src = gw;  dst = gwt; R = DIM; C = FE; }
  else if (which == 1) { src = uw;  dst = uwt; R = DIM; C = FE; }
  else                 { src = dwp; dst = dwt; R = FE;  C = DIM; }
  src += (size_t)e * R * C;
  dst += (size_t)e * R * C;
  int tiles_c = C / 32;
  int r0 = (blockIdx.x / tiles_c) * 256, c0 = (blockIdx.x % tiles_c) * 32;
  int tid = threadIdx.x;
#pragma unroll
  for (int p = 0; p < 8; ++p) {
    int idx = tid + p * 256;
    int row = idx >> 3, fq = (idx & 7) * 4;
    float4 v = *(const float4*)(src + (size_t)(r0 + row) * C + c0 + fq);
    tile[fq + 0][row] = v.x; tile[fq + 1][row] = v.y;
    tile[fq + 2][row] = v.z; tile[fq + 3][row] = v.w;
  }
  __syncthreads();
#pragma unroll
  for (int p = 0; p < 4; ++p) {
    int c = (tid >> 5) + p * 8, ch = (tid & 31) * 8;
    bf16x8 w;
#pragma unroll
    for (int j = 0; j < 8; ++j) w[j] = (__bf16)tile[c][ch + j];
    *(bf16x8*)(dst + (size_t)(c0 + c) * R + r0 + ch) = w;
  }
}

// ---- combine: out[t] = SCALE*(w0*dbuf[p0] + w1*dbuf[p1]) --------------------
__global__ __launch_bounds__(256) void k_combine(
    const __bf16* __restrict__ dbuf, const float* __restrict__ topw,
    const int* __restrict__ invp, float* __restrict__ out) {
  int t = blockIdx.x;
  int c = threadIdx.x * 8;
  int p0 = invp[2 * t], p1 = invp[2 * t + 1];
  float w0 = topw[2 * t] * SCALE_F, w1 = topw[2 * t + 1] * SCALE_F;
  bf16x8 a = *(const bf16x8*)(dbuf + (size_t)p0 * DIM + c);
  bf16x8 b = *(const bf16x8*)(dbuf + (size_t)p1 * DIM + c);
  float4 o0, o1;
  o0.x = w0 * (float)a[0] + w1 * (float)b[0];
  o0.y = w0 * (float)a[1] + w1 * (float)b[1];
  o0.z = w0 * (float)a[2] + w1 * (float)b[2];
  o0.w = w0 * (float)a[3] + w1 * (float)b[3];
  o1.x = w0 * (float)a[4] + w1 * (float)b[4];
  o1.y = w0 * (float)a[5] + w1 * (float)b[5];
  o1.z = w0 * (float)a[6] + w1 * (float)b[6];
  o1.w = w0 * (float)a[7] + w1 * (float)b[7];
  *(float4*)(out + (size_t)t * DIM + c) = o0;
  *(float4*)(out + (size_t)t * DIM + c + 4) = o1;
}

// ================= FAST PATH =================================================

// gate/up fused GEMM + SiLU. BM=256 rows x 128 f-cols ({g,u} each), BK=64,
// 8 waves (2M x 4N): per-wave 128 rows x 32 f x {g,u}. 2-buffer LDS (128KB),
// 4 phases/K-tile, vmcnt(2) once per tile. grid: x=FE/128(8), y=32, z=8.
__global__ __launch_bounds__(512, 2) void k_gateup12(
    const __bf16* __restrict__ xbf, const __bf16* __restrict__ gwt,
    const __bf16* __restrict__ uwt, const int* __restrict__ row_token,
    const int* __restrict__ offsets, __bf16* __restrict__ abuf) {
  int e = blockIdx.z;
  int row_start = offsets[e], row_end = offsets[e + 1];
  int tile_row = row_start + blockIdx.y * 256;
  if (tile_row >= row_end) return;
  int n0 = blockIdx.x * 128;

  __shared__ __align__(16) __bf16 As0[256][64], As1[256][64];
  __shared__ __align__(16) __bf16 Bg0[128][64], Bg1[128][64];
  __shared__ __align__(16) __bf16 Bu0[128][64], Bu1[128][64];
  __shared__ int toks[256];

  int tid = threadIdx.x;
  if (tid < 256) {
    int r = tile_row + tid;
    toks[tid] = (r < row_end) ? row_token[r] : row_token[row_start];
  }
  __syncthreads();

  int wid = tid >> 6, lane = tid & 63;
  int srow = tid >> 3;                 // staging row within 64-row round
  int schunk = tid & 7;                // staging chunk 0..7

  // staging sources (pre-permuted chunk: stored pos p holds global chunk p^(row&7))
  const __bf16* pa0 = xbf + (size_t)toks[srow] * DIM + (schunk ^ (srow & 7)) * 8;
  const __bf16* pa1 = xbf + (size_t)toks[64 + srow] * DIM + (schunk ^ (srow & 7)) * 8;
  const __bf16* pa2 = xbf + (size_t)toks[128 + srow] * DIM + (schunk ^ (srow & 7)) * 8;
  const __bf16* pa3 = xbf + (size_t)toks[192 + srow] * DIM + (schunk ^ (srow & 7)) * 8;
  const __bf16* pg0 = gwt + ((size_t)e * FE + n0 + srow) * DIM + (schunk ^ (srow & 7)) * 8;
  const __bf16* pg1 = gwt + ((size_t)e * FE + n0 + 64 + srow) * DIM + (schunk ^ (srow & 7)) * 8;
  const __bf16* pu0 = uwt + ((size_t)e * FE + n0 + srow) * DIM + (schunk ^ (srow & 7)) * 8;
  const __bf16* pu1 = uwt + ((size_t)e * FE + n0 + 64 + srow) * DIM + (schunk ^ (srow & 7)) * 8;

  f32x4 accg[8][2], accu[8][2];
#pragma unroll
  for (int i = 0; i < 8; ++i)
#pragma unroll
    for (int j = 0; j < 2; ++j) { accg[i][j] = (f32x4)0.f; accu[i][j] = (f32x4)0.f; }

  int wm = (wid >> 2) * 128;           // 0 or 128
  int wf = (wid & 3) * 32;             // 0,32,64,96
  int lr = lane & 15;
  int lr7 = lane & 7;
  int khi = lane >> 4;                 // 0..3
  int c0s = (khi ^ lr7) * 8;           // swizzled elem-offset, K-half 0
  int c1s = ((4 + khi) ^ lr7) * 8;     // K-half 1

  bf16x8 aF[4][2], bgF[2][2], buF[2][2];

  // LDS read macro: fragment at (row, K-half) with read-side swizzle
#define RDA(AS, ROW, KH) (*(const bf16x8*)&AS[ROW][(KH) ? c1s : c0s])

#define STG_A01(AS) do { \
    gll16(pa0, (void*)&AS[wid * 8][0]);       pa0 += 64; \
    gll16(pa1, (void*)&AS[64 + wid * 8][0]);  pa1 += 64; } while (0)
#define STG_A23(AS) do { \
    gll16(pa2, (void*)&AS[128 + wid * 8][0]); pa2 += 64; \
    gll16(pa3, (void*)&AS[192 + wid * 8][0]); pa3 += 64; } while (0)
#define STG_G(BG) do { \
    gll16(pg0, (void*)&BG[wid * 8][0]);       pg0 += 64; \
    gll16(pg1, (void*)&BG[64 + wid * 8][0]);  pg1 += 64; } while (0)
#define STG_U(BU) do { \
    gll16(pu0, (void*)&BU[wid * 8][0]);       pu0 += 64; \
    gll16(pu1, (void*)&BU[64 + wid * 8][0]);  pu1 += 64; } while (0)

#define MFMA_Q(ACC, MH, BF) do { \
    __builtin_amdgcn_s_setprio(1); \
    ACC[(MH)*4+0][0] = MFMA16(aF[0][0], BF[0][0], ACC[(MH)*4+0][0]); \
    ACC[(MH)*4+0][0] = MFMA16(aF[0][1], BF[0][1], ACC[(MH)*4+0][0]); \
    ACC[(MH)*4+0][1] = MFMA16(aF[0][0], BF[1][0], ACC[(MH)*4+0][1]); \
    ACC[(MH)*4+0][1] = MFMA16(aF[0][1], BF[1][1], ACC[(MH)*4+0][1]); \
    ACC[(MH)*4+1][0] = MFMA16(aF[1][0], BF[0][0], ACC[(MH)*4+1][0]); \
    ACC[(MH)*4+1][0] = MFMA16(aF[1][1], BF[0][1], ACC[(MH)*4+1][0]); \
    ACC[(MH)*4+1][1] = MFMA16(aF[1][0], BF[1][0], ACC[(MH)*4+1][1]); \
    ACC[(MH)*4+1][1] = MFMA16(aF[1][1], BF[1][1], ACC[(MH)*4+1][1]); \
    ACC[(MH)*4+2][0] = MFMA16(aF[2][0], BF[0][0], ACC[(MH)*4+2][0]); \
    ACC[(MH)*4+2][0] = MFMA16(aF[2][1], BF[0][1], ACC[(MH)*4+2][0]); \
    ACC[(MH)*4+2][1] = MFMA16(aF[2][0], BF[1][0], ACC[(MH)*4+2][1]); \
    ACC[(MH)*4+2][1] = MFMA16(aF[2][1], BF[1][1], ACC[(MH)*4+2][1]); \
    ACC[(MH)*4+3][0] = MFMA16(aF[3][0], BF[0][0], ACC[(MH)*4+3][0]); \
    ACC[(MH)*4+3][0] = MFMA16(aF[3][1], BF[0][1], ACC[(MH)*4+3][0]); \
    ACC[(MH)*4+3][1] = MFMA16(aF[3][0], BF[1][0], ACC[(MH)*4+3][1]); \
    ACC[(MH)*4+3][1] = MFMA16(aF[3][1], BF[1][1], ACC[(MH)*4+3][1]); \
    __builtin_amdgcn_s_setprio(0); } while (0)

#define LOAD_AL(AS, MH) do { \
    aF[0][0] = RDA(AS, wm + (MH)*64 +  0 + lr, 0); \
    aF[0][1] = RDA(AS, wm + (MH)*64 +  0 + lr, 1); \
    aF[1][0] = RDA(AS, wm + (MH)*64 + 16 + lr, 0); \
    aF[1][1] = RDA(AS, wm + (MH)*64 + 16 + lr, 1); \
    aF[2][0] = RDA(AS, wm + (MH)*64 + 32 + lr, 0); \
    aF[2][1] = RDA(AS, wm + (MH)*64 + 32 + lr, 1); \
    aF[3][0] = RDA(AS, wm + (MH)*64 + 48 + lr, 0); \
    aF[3][1] = RDA(AS, wm + (MH)*64 + 48 + lr, 1); } while (0)

#define LOAD_B(BS, BF) do { \
    BF[0][0] = RDA(BS, wf + lr, 0); \
    BF[0][1] = RDA(BS, wf + lr, 1); \
    BF[1][0] = RDA(BS, wf + 16 + lr, 0); \
    BF[1][1] = RDA(BS, wf + 16 + lr, 1); } while (0)

  // TILE(read bufs; stage bufs): 4 phases
#define TILE(ASR, BGR, BUR, ASS, BGS, BUS)                                  \
  do {                                                                      \
    /* Ph0: m-low x g */                                                    \
    STG_A01(ASS);                                                           \
    VMCNT2; BAR;                                                            \
    LOAD_AL(ASR, 0); LOAD_B(BGR, bgF);                                      \
    LGKM0; SCHED0;                                                          \
    MFMA_Q(accg, 0, bgF);                                                   \
    BAR;                                                                    \
    /* Ph1: m-low x u */                                                    \
    LOAD_B(BUR, buF);                                                       \
    STG_A23(ASS);                                                           \
    BAR;                                                                    \
    LGKM0; SCHED0;                                                          \
    MFMA_Q(accu, 0, buF);                                                   \
    BAR;                                                                    \
    /* Ph2: m-high x g (bgF reused) */                                      \
    LOAD_AL(ASR, 1);                                                        \
    STG_G(BGS);                                                             \
    BAR;                                                                    \
    LGKM0; SCHED0;                                                          \
    MFMA_Q(accg, 1, bgF);                                                   \
    BAR;                                                                    \
    /* Ph3: m-high x u (aF, buF reused) */                                  \
    STG_U(BUS);                                                             \
    BAR;                                                                    \
    MFMA_Q(accu, 1, buF);                                                   \
    BAR;                                                                    \
  } while (0)

  // prologue: stage tile 0 fully into buf0 (8 gll16/thread)
  STG_A01(As0); STG_A23(As0); STG_G(Bg0); STG_U(Bu0);
  // main loop: 32 K-tiles, unroll x2 for static buffers.
  // tile 31 prefetches past-end (into ws, never read) to keep code uniform.
#pragma unroll 1
  for (int it = 0; it < 16; ++it) {
    TILE(As0, Bg0, Bu0, As1, Bg1, Bu1);
    TILE(As1, Bg1, Bu1, As0, Bg0, Bu0);
  }
#undef TILE
#undef LOAD_B
#undef LOAD_AL
#undef MFMA_Q
#undef STG_A01
#undef STG_A23
#undef STG_G
#undef STG_U
#undef RDA

  // epilogue: silu(g)*u -> abuf
  int rowq = (lane >> 4) * 4;
#pragma unroll
  for (int mh = 0; mh < 2; ++mh) {
#pragma unroll
    for (int mi = 0; mi < 4; ++mi) {
#pragma unroll
      for (int ni = 0; ni < 2; ++ni) {
#pragma unroll
        for (int j = 0; j < 4; ++j) {
          int rg = tile_row + wm + mh * 64 + mi * 16 + rowq + j;
          if (rg < row_end) {
            float g = accg[mh * 4 + mi][ni][j], u = accu[mh * 4 + mi][ni][j];
            float sig = 1.f / (1.f + __expf(-g));
            abuf[(size_t)rg * FE + n0 + wf + ni * 16 + lr] = (__bf16)(g * sig * u);
          }
        }
      }
    }
  }
}

// down GEMM -> unweighted bf16 rows into dbuf. 128x128, R8 pipeline + XCD remap.
// grid: 4096 linear. nw=(lin&7)*512+(lin>>3); y=nw&31, x=(nw>>5)&15, e=nw>>9.
__global__ __launch_bounds__(256) void k_down11(
    const __bf16* __restrict__ abuf, const __bf16* __restrict__ dwt,
    const int* __restrict__ offsets, __bf16* __restrict__ dbuf) {
  int lin = blockIdx.x;
  int nw = (lin & 7) * 512 + (lin >> 3);
  int ytile = nw & 31, xt = (nw >> 5) & 15, e = nw >> 9;
  int row_start = offsets[e], row_end = offsets[e + 1];
  int tile_row = row_start + ytile * 128;
  if (tile_row >= row_end) return;
  int n0 = xt * 128;

  __shared__ __align__(16) __bf16 As0[128][BK], As1[128][BK];
  __shared__ __align__(16) __bf16 Bs0[128][BK], Bs1[128][BK];

  int tid = threadIdx.x;
  int wid = tid >> 6, lane = tid & 63;
  int lrow = lane >> 2;
  int lke = (((lane & 3) ^ ((lane >> 3) & 3)) * 8);
  int lks = (((lane >> 4) ^ ((lane >> 1) & 3)) * 8);

  const __bf16* pa0 = abuf + (size_t)(tile_row + wid * 32 + lrow) * FE + lke;
  const __bf16* pa1 = pa0 + (size_t)16 * FE;
  const __bf16* pb0 = dwt + ((size_t)e * DIM + n0 + wid * 32 + lrow) * FE + lke;
  const __bf16* pb1 = pb0 + (size_t)16 * FE;

  f32x4 acc[4][4];
#pragma unroll
  for (int i = 0; i < 4; ++i)
#pragma unroll
    for (int j = 0; j < 4; ++j) acc[i][j] = (f32x4)0.f;

  int lr = lane & 15;
  int wm = (wid >> 1) * 64, wn = (wid & 1) * 64;

  bf16x8 af0, af1, af2, af3, bb0, bb1, bb2, bb3;

#define DN_STAGE(AS, BS)                                     \
  do {                                                       \
    gll16(pa0, (void*)&AS[wid * 32][0]);                     \
    gll16(pa1, (void*)&AS[wid * 32 + 16][0]);                \
    gll16(pb0, (void*)&BS[wid * 32][0]);                     \
    gll16(pb1, (void*)&BS[wid * 32 + 16][0]);                \
    pa0 += BK; pa1 += BK; pb0 += BK; pb1 += BK;              \
  } while (0)

#define DN_LOAD(AS, BS)                                      \
  do {                                                       \
    af0 = *(const bf16x8*)&AS[wm + lr][lks];                 \
    af1 = *(const bf16x8*)&AS[wm + 16 + lr][lks];            \
    af2 = *(const bf16x8*)&AS[wm + 32 + lr][lks];            \
    af3 = *(const bf16x8*)&AS[wm + 48 + lr][lks];            \
    bb0 = *(const bf16x8*)&BS[wn + lr][lks];                 \
    bb1 = *(const bf16x8*)&BS[wn + 16 + lr][lks];            \
    bb2 = *(const bf16x8*)&BS[wn + 32 + lr][lks];            \
    bb3 = *(const bf16x8*)&BS[wn + 48 + lr][lks];            \
  } while (0)

#define DN_MFMA()                                            \
  do {                                                       \
    __builtin_amdgcn_s_setprio(1);                           \
    acc[0][0] = MFMA16(af0, bb0, acc[0][0]);                 \
    acc[1][0] = MFMA16(af1, bb0, acc[1][0]);                 \
    acc[2][0] = MFMA16(af2, bb0, acc[2][0]);                 \
    acc[3][0] = MFMA16(af3, bb0, acc[3][0]);                 \
    acc[0][1] = MFMA16(af0, bb1, acc[0][1]);                 \
    acc[1][1] = MFMA16(af1, bb1, acc[1][1]);                 \
    acc[2][1] = MFMA16(af2, bb1, acc[2][1]);                 \
    acc[3][1] = MFMA16(af3, bb1, acc[3][1]);                 \
    acc[0][2] = MFMA16(af0, bb2, acc[0][2]);                 \
    acc[1][2] = MFMA16(af1, bb2, acc[1][2]);                 \
    acc[2][2] = MFMA16(af2, bb2, acc[2][2]);                 \
    acc[3][2] = MFMA16(af3, bb2, acc[3][2]);                 \
    acc[0][3] = MFMA16(af0, bb3, acc[0][3]);                 \
    acc[1][3] = MFMA16(af1, bb3, acc[1][3]);                 \
    acc[2][3] = MFMA16(af2, bb3, acc[2][3]);                 \
    acc[3][3] = MFMA16(af3, bb3, acc[3][3]);                 \
    __builtin_amdgcn_s_setprio(0);                           \
  } while (0)

  DN_STAGE(As0, Bs0);
  DN_STAGE(As1, Bs1);
#pragma unroll 1
  for (int it = 0; it < 15; ++it) {
    VMCNT4; BAR;
    DN_LOAD(As0, Bs0);
    LGKM0; SCHED0; BAR;
    DN_STAGE(As0, Bs0);
    DN_MFMA();
    VMCNT4; BAR;
    DN_LOAD(As1, Bs1);
    LGKM0; SCHED0; BAR;
    DN_STAGE(As1, Bs1);
    DN_MFMA();
  }
  VMCNT4; BAR;
  DN_LOAD(As0, Bs0);
  DN_MFMA();
  VMCNT0; BAR;
  DN_LOAD(As1, Bs1);
  DN_MFMA();
#undef DN_STAGE
#undef DN_LOAD
#undef DN_MFMA

  int rowq = (lane >> 4) * 4;
#pragma unroll
  for (int mi = 0; mi < 4; ++mi) {
#pragma unroll
    for (int j = 0; j < 4; ++j) {
      int rg = tile_row + wm + mi * 16 + rowq + j;
      if (rg < row_end) {
#pragma unroll
        for (int ni = 0; ni < 4; ++ni) {
          dbuf[(size_t)rg * DIM + n0 + wn + ni * 16 + lr] = (__bf16)acc[mi][ni][j];
        }
      }
    }
  }
}

// ================= FALLBACK PATH (round-1 kernels) ============================

#define PAD 8
__global__ __launch_bounds__(256) void k_gateup_fb(
    const __bf16* __restrict__ xbf, const float* __restrict__ gw,
    const float* __restrict__ uw, const int* __restrict__ row_token,
    const int* __restrict__ offsets, __bf16* __restrict__ abuf) {
  int e = blockIdx.z;
  int row_start = offsets[e], row_end = offsets[e + 1];
  int tile_row = row_start + blockIdx.y * 128;
  if (tile_row >= row_end) return;
  int n0 = blockIdx.x * 128;

  __shared__ __align__(16) __bf16 As[128][BK + PAD];
  __shared__ __align__(16) __bf16 Bgs[128][BK + PAD];
  __shared__ __align__(16) __bf16 Bus[128][BK + PAD];
  __shared__ int toks[128];

  int tid = threadIdx.x;
  if (tid < 128) {
    int r = tile_row + tid;
    toks[tid] = (r < row_end) ? row_token[r] : row_token[row_start];
  }
  __syncthreads();

  f32x4 accg[4][4]; f32x4 accu[4][4];
#pragma unroll
  for (int i = 0; i < 4; ++i)
#pragma unroll
    for (int j = 0; j < 4; ++j) { accg[i][j] = (f32x4)0.f; accu[i][j] = (f32x4)0.f; }

  int wid = tid >> 6, lane = tid & 63;
  int wm = (wid >> 1) * 64, wn = (wid & 1) * 64;
  int lr = lane & 15, lk = (lane >> 4) * 8;

  const float* gbase = gw + (size_t)e * DIM * FE + n0;
  const float* ubase = uw + (size_t)e * DIM * FE + n0;
  int n4 = (tid & 31) * 4;
  int kb = tid >> 5;

  for (int k0 = 0; k0 < DIM; k0 += BK) {
#pragma unroll
    for (int p = 0; p < 2; ++p) {
      int g = tid + p * 256;
      int r = g >> 2, kk = (g & 3) * 8;
      *(bf16x8*)&As[r][kk] = *(const bf16x8*)(xbf + (size_t)toks[r] * DIM + k0 + kk);
    }
#pragma unroll
    for (int p = 0; p < 4; ++p) {
      int k = kb + p * 8;
      const float4 vg = *(const float4*)(gbase + (size_t)(k0 + k) * FE + n4);
      const float4 vu = *(const float4*)(ubase + (size_t)(k0 + k) * FE + n4);
      Bgs[n4 + 0][k] = (__bf16)vg.x; Bgs[n4 + 1][k] = (__bf16)vg.y;
      Bgs[n4 + 2][k] = (__bf16)vg.z; Bgs[n4 + 3][k] = (__bf16)vg.w;
      Bus[n4 + 0][k] = (__bf16)vu.x; Bus[n4 + 1][k] = (__bf16)vu.y;
      Bus[n4 + 2][k] = (__bf16)vu.z; Bus[n4 + 3][k] = (__bf16)vu.w;
    }
    __syncthreads();

    bf16x8 af[4];
#pragma unroll
    for (int mi = 0; mi < 4; ++mi)
      af[mi] = *(const bf16x8*)&As[wm + mi * 16 + lr][lk];
#pragma unroll
    for (int ni = 0; ni < 4; ++ni) {
      bf16x8 bg = *(const bf16x8*)&Bgs[wn + ni * 16 + lr][lk];
      bf16x8 bu = *(const bf16x8*)&Bus[wn + ni * 16 + lr][lk];
#pragma unroll
      for (int mi = 0; mi < 4; ++mi) {
        accg[mi][ni] = MFMA16(af[mi], bg, accg[mi][ni]);
        accu[mi][ni] = MFMA16(af[mi], bu, accu[mi][ni]);
      }
    }
    __syncthreads();
  }

  int rowq = (lane >> 4) * 4;
#pragma unroll
  for (int mi = 0; mi < 4; ++mi) {
#pragma unroll
    for (int ni = 0; ni < 4; ++ni) {
#pragma unroll
      for (int j = 0; j < 4; ++j) {
        int rg = tile_row + wm + mi * 16 + rowq + j;
        if (rg < row_end) {
          float g = accg[mi][ni][j], u = accu[mi][ni][j];
          float sig = 1.f / (1.f + __expf(-g));
          abuf[(size_t)rg * FE + n0 + wn + ni * 16 + lr] = (__bf16)(g * sig * u);
        }
      }
    }
  }
}

__global__ __launch_bounds__(256) void k_down_fb(
    const __bf16* __restrict__ abuf, const float* __restrict__ dw,
    const int* __restrict__ row_token, const float* __restrict__ row_wt,
    const int* __restrict__ offsets, float* __restrict__ out) {
  int e = blockIdx.z;
  int row_start = offsets[e], row_end = offsets[e + 1];
  int tile_row = row_start + blockIdx.y * 128;
  if (tile_row >= row_end) return;
  int n0 = blockIdx.x * 128;

  __shared__ __align__(16) __bf16 As[128][BK + PAD];
  __shared__ __align__(16) __bf16 Bs[128][BK + PAD];

  int tid = threadIdx.x;
  f32x4 acc[4][4];
#pragma unroll
  for (int i = 0; i < 4; ++i)
#pragma unroll
    for (int j = 0; j < 4; ++j) acc[i][j] = (f32x4)0.f;

  int wid = tid >> 6, lane = tid & 63;
  int wm = (wid >> 1) * 64, wn = (wid & 1) * 64;
  int lr = lane & 15, lk = (lane >> 4) * 8;

  const float* dbase = dw + (size_t)e * FE * DIM + n0;
  int n4 = (tid & 31) * 4;
  int kb = tid >> 5;

  for (int k0 = 0; k0 < FE; k0 += BK) {
#pragma unroll
    for (int p = 0; p < 2; ++p) {
      int g = tid + p * 256;
      int r = g >> 2, kk = (g & 3) * 8;
      *(bf16x8*)&As[r][kk] = *(const bf16x8*)(abuf + (size_t)(tile_row + r) * FE + k0 + kk);
    }
#pragma unroll
    for (int p = 0; p < 4; ++p) {
      int k = kb + p * 8;
      const float4 vb = *(const float4*)(dbase + (size_t)(k0 + k) * DIM + n4);
      Bs[n4 + 0][k] = (__bf16)vb.x; Bs[n4 + 1][k] = (__bf16)vb.y;
      Bs[n4 + 2][k] = (__bf16)vb.z; Bs[n4 + 3][k] = (__bf16)vb.w;
    }
    __syncthreads();

    bf16x8 af[4];
#pragma unroll
    for (int mi = 0; mi < 4; ++mi)
      af[mi] = *(const bf16x8*)&As[wm + mi * 16 + lr][lk];
#pragma unroll
    for (int ni = 0; ni < 4; ++ni) {
      bf16x8 bb = *(const bf16x8*)&Bs[wn + ni * 16 + lr][lk];
#pragma unroll
      for (int mi = 0; mi < 4; ++mi)
        acc[mi][ni] = MFMA16(af[mi], bb, acc[mi][ni]);
    }
    __syncthreads();
  }

  int rowq = (lane >> 4) * 4;
#pragma unroll
  for (int mi = 0; mi < 4; ++mi) {
#pragma unroll
    for (int j = 0; j < 4; ++j) {
      int rg = tile_row + wm + mi * 16 + rowq + j;
      if (rg < row_end) {
        int tok = row_token[rg];
        float w = row_wt[rg];
#pragma unroll
        for (int ni = 0; ni < 4; ++ni) {
          atomicAdd(&out[(size_t)tok * DIM + n0 + wn + ni * 16 + lr],
                    acc[mi][ni][j] * w);
        }
      }
    }
  }
}

extern "C" void kernel_launch(void* const* d_in, const int* in_sizes, int n_in,
                              void* d_out, int out_size, void* d_ws, size_t ws_size,
                              hipStream_t stream) {
  const float* x  = (const float*)d_in[0];
  const float* rw = (const float*)d_in[1];
  const float* nw = (const float*)d_in[2];
  const float* gw = (const float*)d_in[3];
  const float* uw = (const float*)d_in[4];
  const float* dwp= (const float*)d_in[5];
  float* out = (float*)d_out;

  char* p = (char*)d_ws;
  int* counts    = (int*)p;
  int* cursor    = (int*)(p + 32);
  int* offsets   = (int*)(p + 64);
  int* topi      = (int*)(p + 256);
  float* topw    = (float*)(p + 256 + 32768);
  int* row_token = (int*)(p + 256 + 65536);
  float* row_wt  = (float*)(p + 256 + 98304);
  int* invp      = (int*)(p + 256 + 131072);
  __bf16* xbf    = (__bf16*)(p + 256 + 163840);
  __bf16* abuf   = xbf + (size_t)TOK * DIM;
  __bf16* gwt    = abuf + ((size_t)2 * TOK + 256) * FE;
  __bf16* uwt    = gwt + (size_t)NE * DIM * FE;
  __bf16* dwt    = uwt + (size_t)NE * DIM * FE;
  __bf16* dbuf   = gwt;   // overlay: gwt/uwt dead after gateup

  size_t need = 256 + 163840 +
                ((size_t)TOK * DIM + ((size_t)2 * TOK + 256) * FE) * 2 +
                3 * (size_t)NE * DIM * FE * 2;
  bool fast = ws_size >= need;

  hipMemsetAsync(p, 0, 64, stream);
  if (!fast)
    hipMemsetAsync(d_out, 0, (size_t)TOK * DIM * sizeof(float), stream);

  if (fast) {
    k_cvt2<<<dim3(256, 24), 256, 0, stream>>>(gw, uw, dwp, gwt, uwt, dwt);
  }

  k_router<<<TOK, 256, 0, stream>>>(x, rw, nw, xbf, topi, topw, counts);
  k_prefix<<<1, 64, 0, stream>>>(counts, offsets, cursor);
  k_place<<<(TOK + 255) / 256, 256, 0, stream>>>(topi, topw, cursor, row_token, row_wt, invp);

  if (fast) {
    k_gateup12<<<dim3(FE / 128, 32, NE), 512, 0, stream>>>(xbf, gwt, uwt, row_token, offsets, abuf);
    k_down11<<<4096, 256, 0, stream>>>(abuf, dwt, offsets, dbuf);
    k_combine<<<TOK, 256, 0, stream>>>(dbuf, topw, invp, out);
  } else {
    k_gateup_fb<<<dim3(FE / 128, 32, NE), 256, 0, stream>>>(xbf, gw, uw, row_token, offsets, abuf);
    k_down_fb<<<dim3(DIM / 128, 32, NE), 256, 0, stream>>>(abuf, dwp, row_token, row_wt, offsets, out);
  }
}

// Round 13
// 321.577 us; speedup vs baseline: 1.1809x; 1.1809x over previous
//
#include <hip/hip_runtime.h>
#include <hip/hip_bf16.h>

// Sparse MoE v13: R8 GEMMs + XCD-affine remap on BOTH GEMMs; cvt+router fused
// into one grid-partitioned kernel (independent work, overlapped); prefix+place
// merged into a single 1-block kernel with LDS cursors. dbuf+combine epilogue.
// T=4096 tokens, D=2048, E=8, F_E=1024, top-2, SCALE=4.

#define TOK 4096
#define DIM 2048
#define NE 8
#define FE 1024
#define SCALE_F 4.0f
#define BK 32

typedef __bf16 bf16x8 __attribute__((ext_vector_type(8)));
typedef __bf16 bf16x4 __attribute__((ext_vector_type(4)));
typedef float f32x4 __attribute__((ext_vector_type(4)));

__device__ __forceinline__ void gll16(const void* g, void* l) {
  __builtin_amdgcn_global_load_lds(
      (const __attribute__((address_space(1))) unsigned int*)g,
      (__attribute__((address_space(3))) unsigned int*)l, 16, 0, 0);
}

#define MFMA16(a, b, c) __builtin_amdgcn_mfma_f32_16x16x32_bf16((a), (b), (c), 0, 0, 0)
#define VMCNT4 asm volatile("s_waitcnt vmcnt(4)" ::: "memory")
#define VMCNT0 asm volatile("s_waitcnt vmcnt(0)" ::: "memory")
#define LGKM0  asm volatile("s_waitcnt lgkmcnt(0)" ::: "memory")
#define SCHED0 __builtin_amdgcn_sched_barrier(0)
#define BAR    __builtin_amdgcn_s_barrier()

// ---- fused: blocks [0,TOK) = router; blocks [TOK, TOK+6144) = weight convert.
// Router: RMSNorm -> logits -> softmax top2 -> counts; x->bf16.
// Convert: [R][C] f32 -> [C][R] bf16, 256r x 32c tiles (from R11 k_cvt2).
__global__ __launch_bounds__(256) void k_fused_cvt_router(
    const float* __restrict__ x, const float* __restrict__ rw,
    const float* __restrict__ nwt, __bf16* __restrict__ xbf,
    int* __restrict__ topi, float* __restrict__ topw, int* __restrict__ counts,
    const float* __restrict__ gw, const float* __restrict__ uw,
    const float* __restrict__ dwp, __bf16* __restrict__ gwt,
    __bf16* __restrict__ uwt, __bf16* __restrict__ dwt) {
  __shared__ __align__(16) float smem[32 * 257];
  int tid = threadIdx.x;

  if (blockIdx.x < TOK) {
    // ---------------- router path ----------------
    int t = blockIdx.x;
    const float* xr = x + (size_t)t * DIM;
    float ssq = 0.f;
    float pe[NE];
#pragma unroll
    for (int e = 0; e < NE; ++e) pe[e] = 0.f;

#pragma unroll
    for (int i = 0; i < 2; ++i) {
      int c4 = tid + i * 256;
      float4 v = ((const float4*)xr)[c4];
      int c = c4 * 4;
      bf16x4 b;
      b[0] = (__bf16)v.x; b[1] = (__bf16)v.y; b[2] = (__bf16)v.z; b[3] = (__bf16)v.w;
      *(bf16x4*)(xbf + (size_t)t * DIM + c) = b;
      float xs[4] = {v.x, v.y, v.z, v.w};
#pragma unroll
      for (int j = 0; j < 4; ++j) {
        float xc = xs[j];
        ssq += xc * xc;
        float m = nwt[c + j] * xc;
#pragma unroll
        for (int e = 0; e < NE; ++e) pe[e] += m * rw[e * DIM + c + j];
      }
    }
#pragma unroll
    for (int off = 32; off > 0; off >>= 1) {
      ssq += __shfl_down(ssq, off);
#pragma unroll
      for (int e = 0; e < NE; ++e) pe[e] += __shfl_down(pe[e], off);
    }
    float (*red)[NE + 1] = (float (*)[NE + 1])smem;
    int wid = tid >> 6, lane = tid & 63;
    if (lane == 0) {
      red[wid][0] = ssq;
#pragma unroll
      for (int e = 0; e < NE; ++e) red[wid][1 + e] = pe[e];
    }
    __syncthreads();
    if (tid == 0) {
      float s = red[0][0] + red[1][0] + red[2][0] + red[3][0];
      float rs = rsqrtf(s / (float)DIM + 1e-6f);
      float l[NE];
#pragma unroll
      for (int e = 0; e < NE; ++e)
        l[e] = (red[0][1 + e] + red[1][1 + e] + red[2][1 + e] + red[3][1 + e]) * rs;
      int i1 = 0;
#pragma unroll
      for (int e = 1; e < NE; ++e) if (l[e] > l[i1]) i1 = e;
      int i2 = -1;
#pragma unroll
      for (int e = 0; e < NE; ++e) if (e != i1 && (i2 < 0 || l[e] > l[i2])) i2 = e;
      float e2 = __expf(l[i2] - l[i1]);
      float inv = 1.f / (1.f + e2);
      topi[2 * t] = i1; topi[2 * t + 1] = i2;
      topw[2 * t] = inv; topw[2 * t + 1] = e2 * inv;
      atomicAdd(&counts[i1], 1);
      atomicAdd(&counts[i2], 1);
    }
  } else {
    // ---------------- convert path ----------------
    int bx = blockIdx.x - TOK;           // 0..6143
    int m = bx >> 8;                     // 0..23
    int tilex = bx & 255;
    int which = m >> 3, e = m & 7;
    const float* src; __bf16* dst; int R, C;
    if (which == 0)      { src = gw;  dst = gwt; R = DIM; C = FE; }
    else if (which == 1) { src = uw;  dst = uwt; R = DIM; C = FE; }
    else                 { src = dwp; dst = dwt; R = FE;  C = DIM; }
    src += (size_t)e * R * C;
    dst += (size_t)e * R * C;
    float (*tile)[257] = (float (*)[257])smem;
    int tiles_c = C / 32;
    int r0 = (tilex / tiles_c) * 256, c0 = (tilex % tiles_c) * 32;
#pragma unroll
    for (int p = 0; p < 8; ++p) {
      int idx = tid + p * 256;
      int row = idx >> 3, fq = (idx & 7) * 4;
      float4 v = *(const float4*)(src + (size_t)(r0 + row) * C + c0 + fq);
      tile[fq + 0][row] = v.x; tile[fq + 1][row] = v.y;
      tile[fq + 2][row] = v.z; tile[fq + 3][row] = v.w;
    }
    __syncthreads();
#pragma unroll
    for (int p = 0; p < 4; ++p) {
      int c = (tid >> 5) + p * 8, ch = (tid & 31) * 8;
      bf16x8 w;
#pragma unroll
      for (int j = 0; j < 8; ++j) w[j] = (__bf16)tile[c][ch + j];
      *(bf16x8*)(dst + (size_t)(c0 + c) * R + r0 + ch) = w;
    }
  }
}

// ---- merged prefix + place: 1 block, LDS cursors ----------------------------
__global__ __launch_bounds__(256) void k_prefix_place(
    const int* __restrict__ counts, int* __restrict__ offsets,
    const int* __restrict__ topi, const float* __restrict__ topw,
    int* __restrict__ row_token, float* __restrict__ row_wt,
    int* __restrict__ invp) {
  __shared__ int lcur[NE];
  int tid = threadIdx.x;
  if (tid == 0) {
    int acc = 0;
    for (int e = 0; e < NE; ++e) {
      offsets[e] = acc;
      lcur[e] = acc;
      acc += counts[e];
    }
    offsets[NE] = acc;
  }
  __syncthreads();
  for (int t = tid; t < TOK; t += 256) {
#pragma unroll
    for (int s = 0; s < 2; ++s) {
      int e = topi[2 * t + s];
      int pos = atomicAdd(&lcur[e], 1);
      row_token[pos] = t;
      row_wt[pos] = topw[2 * t + s] * SCALE_F;
      invp[2 * t + s] = pos;
    }
  }
}

// ---- combine: out[t] = SCALE*(w0*dbuf[p0] + w1*dbuf[p1]) --------------------
__global__ __launch_bounds__(256) void k_combine(
    const __bf16* __restrict__ dbuf, const float* __restrict__ topw,
    const int* __restrict__ invp, float* __restrict__ out) {
  int t = blockIdx.x;
  int c = threadIdx.x * 8;
  int p0 = invp[2 * t], p1 = invp[2 * t + 1];
  float w0 = topw[2 * t] * SCALE_F, w1 = topw[2 * t + 1] * SCALE_F;
  bf16x8 a = *(const bf16x8*)(dbuf + (size_t)p0 * DIM + c);
  bf16x8 b = *(const bf16x8*)(dbuf + (size_t)p1 * DIM + c);
  float4 o0, o1;
  o0.x = w0 * (float)a[0] + w1 * (float)b[0];
  o0.y = w0 * (float)a[1] + w1 * (float)b[1];
  o0.z = w0 * (float)a[2] + w1 * (float)b[2];
  o0.w = w0 * (float)a[3] + w1 * (float)b[3];
  o1.x = w0 * (float)a[4] + w1 * (float)b[4];
  o1.y = w0 * (float)a[5] + w1 * (float)b[5];
  o1.z = w0 * (float)a[6] + w1 * (float)b[6];
  o1.w = w0 * (float)a[7] + w1 * (float)b[7];
  *(float4*)(out + (size_t)t * DIM + c) = o0;
  *(float4*)(out + (size_t)t * DIM + c + 4) = o1;
}

// ================= FAST PATH (R8 GEMMs + XCD remap on both) ==================
// XCD remap: nw = (lin&7)*512 + (lin>>3); y=nw&31 (inner), x=(nw>>5)&15 (mid),
// e=nw>>9 (expert == XCD group).  Verified: FETCH 147->75 MB (R9).
// Bank swizzle (verified conflict-free): stage src chunk ((lane&3)^((lane>>3)&3))*8,
// read chunk ((lane>>4)^((lane>>1)&3))*8.

// gate/up fused GEMM + SiLU, 128x64 tile, counted-vmcnt 2-buffer pipeline.
// grid: 4096 linear.
__global__ __launch_bounds__(256) void k_gateup13(
    const __bf16* __restrict__ xbf, const __bf16* __restrict__ gwt,
    const __bf16* __restrict__ uwt, const int* __restrict__ row_token,
    const int* __restrict__ offsets, __bf16* __restrict__ abuf) {
  int lin = blockIdx.x;
  int nw = (lin & 7) * 512 + (lin >> 3);
  int ytile = nw & 31, xt = (nw >> 5) & 15, e = nw >> 9;
  int row_start = offsets[e], row_end = offsets[e + 1];
  int tile_row = row_start + ytile * 128;
  if (tile_row >= row_end) return;
  int n0 = xt * 64;

  __shared__ __align__(16) __bf16 As0[128][BK], As1[128][BK];
  __shared__ __align__(16) __bf16 Bg0[64][BK],  Bg1[64][BK];
  __shared__ __align__(16) __bf16 Bu0[64][BK],  Bu1[64][BK];
  __shared__ int toks[128];

  int tid = threadIdx.x;
  if (tid < 128) {
    int r = tile_row + tid;
    toks[tid] = (r < row_end) ? row_token[r] : row_token[row_start];
  }
  __syncthreads();

  int wid = tid >> 6, lane = tid & 63;
  int lrow = lane >> 2;
  int lke = (((lane & 3) ^ ((lane >> 3) & 3)) * 8);
  int lks = (((lane >> 4) ^ ((lane >> 1) & 3)) * 8);

  const __bf16* pa0 = xbf + (size_t)toks[wid * 32 + lrow] * DIM + lke;
  const __bf16* pa1 = xbf + (size_t)toks[wid * 32 + 16 + lrow] * DIM + lke;
  const __bf16* pg = gwt + ((size_t)e * FE + n0 + wid * 16 + lrow) * DIM + lke;
  const __bf16* pu = uwt + ((size_t)e * FE + n0 + wid * 16 + lrow) * DIM + lke;

  f32x4 accg[4][2], accu[4][2];
#pragma unroll
  for (int i = 0; i < 4; ++i)
#pragma unroll
    for (int j = 0; j < 2; ++j) { accg[i][j] = (f32x4)0.f; accu[i][j] = (f32x4)0.f; }

  int lr = lane & 15;
  int wm = (wid >> 1) * 64, wn = (wid & 1) * 32;

  bf16x8 af0, af1, af2, af3, bgv0, bgv1, buv0, buv1;

#define GU_STAGE(AS, BG, BU)                                 \
  do {                                                       \
    gll16(pa0, (void*)&AS[wid * 32][0]);                     \
    gll16(pa1, (void*)&AS[wid * 32 + 16][0]);                \
    gll16(pg, (void*)&BG[wid * 16][0]);                      \
    gll16(pu, (void*)&BU[wid * 16][0]);                      \
    pa0 += BK; pa1 += BK; pg += BK; pu += BK;                \
  } while (0)

#define GU_LOAD(AS, BG, BU)                                  \
  do {                                                       \
    af0 = *(const bf16x8*)&AS[wm + lr][lks];                 \
    af1 = *(const bf16x8*)&AS[wm + 16 + lr][lks];            \
    af2 = *(const bf16x8*)&AS[wm + 32 + lr][lks];            \
    af3 = *(const bf16x8*)&AS[wm + 48 + lr][lks];            \
    bgv0 = *(const bf16x8*)&BG[wn + lr][lks];                \
    bgv1 = *(const bf16x8*)&BG[wn + 16 + lr][lks];           \
    buv0 = *(const bf16x8*)&BU[wn + lr][lks];                \
    buv1 = *(const bf16x8*)&BU[wn + 16 + lr][lks];           \
  } while (0)

#define GU_MFMA()                                            \
  do {                                                       \
    __builtin_amdgcn_s_setprio(1);                           \
    accg[0][0] = MFMA16(af0, bgv0, accg[0][0]);              \
    accg[0][1] = MFMA16(af0, bgv1, accg[0][1]);              \
    accu[0][0] = MFMA16(af0, buv0, accu[0][0]);              \
    accu[0][1] = MFMA16(af0, buv1, accu[0][1]);              \
    accg[1][0] = MFMA16(af1, bgv0, accg[1][0]);              \
    accg[1][1] = MFMA16(af1, bgv1, accg[1][1]);              \
    accu[1][0] = MFMA16(af1, buv0, accu[1][0]);              \
    accu[1][1] = MFMA16(af1, buv1, accu[1][1]);              \
    accg[2][0] = MFMA16(af2, bgv0, accg[2][0]);              \
    accg[2][1] = MFMA16(af2, bgv1, accg[2][1]);              \
    accu[2][0] = MFMA16(af2, buv0, accu[2][0]);              \
    accu[2][1] = MFMA16(af2, buv1, accu[2][1]);              \
    accg[3][0] = MFMA16(af3, bgv0, accg[3][0]);              \
    accg[3][1] = MFMA16(af3, bgv1, accg[3][1]);              \
    accu[3][0] = MFMA16(af3, buv0, accu[3][0]);              \
    accu[3][1] = MFMA16(af3, buv1, accu[3][1]);              \
    __builtin_amdgcn_s_setprio(0);                           \
  } while (0)

  GU_STAGE(As0, Bg0, Bu0);
  GU_STAGE(As1, Bg1, Bu1);
#pragma unroll 1
  for (int it = 0; it < 31; ++it) {
    VMCNT4; BAR;
    GU_LOAD(As0, Bg0, Bu0);
    LGKM0; SCHED0; BAR;
    GU_STAGE(As0, Bg0, Bu0);
    GU_MFMA();
    VMCNT4; BAR;
    GU_LOAD(As1, Bg1, Bu1);
    LGKM0; SCHED0; BAR;
    GU_STAGE(As1, Bg1, Bu1);
    GU_MFMA();
  }
  VMCNT4; BAR;
  GU_LOAD(As0, Bg0, Bu0);
  GU_MFMA();
  VMCNT0; BAR;
  GU_LOAD(As1, Bg1, Bu1);
  GU_MFMA();
#undef GU_STAGE
#undef GU_LOAD
#undef GU_MFMA

  int rowq = (lane >> 4) * 4;
  f32x4* ag = &accg[0][0];
  f32x4* au = &accu[0][0];
#pragma unroll
  for (int mi = 0; mi < 4; ++mi) {
#pragma unroll
    for (int ni = 0; ni < 2; ++ni) {
#pragma unroll
      for (int j = 0; j < 4; ++j) {
        int rg = tile_row + wm + mi * 16 + rowq + j;
        if (rg < row_end) {
          float g = ag[mi * 2 + ni][j], u = au[mi * 2 + ni][j];
          float sig = 1.f / (1.f + __expf(-g));
          abuf[(size_t)rg * FE + n0 + wn + ni * 16 + lr] = (__bf16)(g * sig * u);
        }
      }
    }
  }
}

// down GEMM -> unweighted bf16 rows into dbuf. 128x128, R8 pipeline + XCD remap.
// grid: 4096 linear.
__global__ __launch_bounds__(256) void k_down11(
    const __bf16* __restrict__ abuf, const __bf16* __restrict__ dwt,
    const int* __restrict__ offsets, __bf16* __restrict__ dbuf) {
  int lin = blockIdx.x;
  int nw = (lin & 7) * 512 + (lin >> 3);
  int ytile = nw & 31, xt = (nw >> 5) & 15, e = nw >> 9;
  int row_start = offsets[e], row_end = offsets[e + 1];
  int tile_row = row_start + ytile * 128;
  if (tile_row >= row_end) return;
  int n0 = xt * 128;

  __shared__ __align__(16) __bf16 As0[128][BK], As1[128][BK];
  __shared__ __align__(16) __bf16 Bs0[128][BK], Bs1[128][BK];

  int tid = threadIdx.x;
  int wid = tid >> 6, lane = tid & 63;
  int lrow = lane >> 2;
  int lke = (((lane & 3) ^ ((lane >> 3) & 3)) * 8);
  int lks = (((lane >> 4) ^ ((lane >> 1) & 3)) * 8);

  const __bf16* pa0 = abuf + (size_t)(tile_row + wid * 32 + lrow) * FE + lke;
  const __bf16* pa1 = pa0 + (size_t)16 * FE;
  const __bf16* pb0 = dwt + ((size_t)e * DIM + n0 + wid * 32 + lrow) * FE + lke;
  const __bf16* pb1 = pb0 + (size_t)16 * FE;

  f32x4 acc[4][4];
#pragma unroll
  for (int i = 0; i < 4; ++i)
#pragma unroll
    for (int j = 0; j < 4; ++j) acc[i][j] = (f32x4)0.f;

  int lr = lane & 15;
  int wm = (wid >> 1) * 64, wn = (wid & 1) * 64;

  bf16x8 af0, af1, af2, af3, bb0, bb1, bb2, bb3;

#define DN_STAGE(AS, BS)                                     \
  do {                                                       \
    gll16(pa0, (void*)&AS[wid * 32][0]);                     \
    gll16(pa1, (void*)&AS[wid * 32 + 16][0]);                \
    gll16(pb0, (void*)&BS[wid * 32][0]);                     \
    gll16(pb1, (void*)&BS[wid * 32 + 16][0]);                \
    pa0 += BK; pa1 += BK; pb0 += BK; pb1 += BK;              \
  } while (0)

#define DN_LOAD(AS, BS)                                      \
  do {                                                       \
    af0 = *(const bf16x8*)&AS[wm + lr][lks];                 \
    af1 = *(const bf16x8*)&AS[wm + 16 + lr][lks];            \
    af2 = *(const bf16x8*)&AS[wm + 32 + lr][lks];            \
    af3 = *(const bf16x8*)&AS[wm + 48 + lr][lks];            \
    bb0 = *(const bf16x8*)&BS[wn + lr][lks];                 \
    bb1 = *(const bf16x8*)&BS[wn + 16 + lr][lks];            \
    bb2 = *(const bf16x8*)&BS[wn + 32 + lr][lks];            \
    bb3 = *(const bf16x8*)&BS[wn + 48 + lr][lks];            \
  } while (0)

#define DN_MFMA()                                            \
  do {                                                       \
    __builtin_amdgcn_s_setprio(1);                           \
    acc[0][0] = MFMA16(af0, bb0, acc[0][0]);                 \
    acc[1][0] = MFMA16(af1, bb0, acc[1][0]);                 \
    acc[2][0] = MFMA16(af2, bb0, acc[2][0]);                 \
    acc[3][0] = MFMA16(af3, bb0, acc[3][0]);                 \
    acc[0][1] = MFMA16(af0, bb1, acc[0][1]);                 \
    acc[1][1] = MFMA16(af1, bb1, acc[1][1]);                 \
    acc[2][1] = MFMA16(af2, bb1, acc[2][1]);                 \
    acc[3][1] = MFMA16(af3, bb1, acc[3][1]);                 \
    acc[0][2] = MFMA16(af0, bb2, acc[0][2]);                 \
    acc[1][2] = MFMA16(af1, bb2, acc[1][2]);                 \
    acc[2][2] = MFMA16(af2, bb2, acc[2][2]);                 \
    acc[3][2] = MFMA16(af3, bb2, acc[3][2]);                 \
    acc[0][3] = MFMA16(af0, bb3, acc[0][3]);                 \
    acc[1][3] = MFMA16(af1, bb3, acc[1][3]);                 \
    acc[2][3] = MFMA16(af2, bb3, acc[2][3]);                 \
    acc[3][3] = MFMA16(af3, bb3, acc[3][3]);                 \
    __builtin_amdgcn_s_setprio(0);                           \
  } while (0)

  DN_STAGE(As0, Bs0);
  DN_STAGE(As1, Bs1);
#pragma unroll 1
  for (int it = 0; it < 15; ++it) {
    VMCNT4; BAR;
    DN_LOAD(As0, Bs0);
    LGKM0; SCHED0; BAR;
    DN_STAGE(As0, Bs0);
    DN_MFMA();
    VMCNT4; BAR;
    DN_LOAD(As1, Bs1);
    LGKM0; SCHED0; BAR;
    DN_STAGE(As1, Bs1);
    DN_MFMA();
  }
  VMCNT4; BAR;
  DN_LOAD(As0, Bs0);
  DN_MFMA();
  VMCNT0; BAR;
  DN_LOAD(As1, Bs1);
  DN_MFMA();
#undef DN_STAGE
#undef DN_LOAD
#undef DN_MFMA

  int rowq = (lane >> 4) * 4;
#pragma unroll
  for (int mi = 0; mi < 4; ++mi) {
#pragma unroll
    for (int j = 0; j < 4; ++j) {
      int rg = tile_row + wm + mi * 16 + rowq + j;
      if (rg < row_end) {
#pragma unroll
        for (int ni = 0; ni < 4; ++ni) {
          dbuf[(size_t)rg * DIM + n0 + wn + ni * 16 + lr] = (__bf16)acc[mi][ni][j];
        }
      }
    }
  }
}

// ================= FALLBACK PATH (round-1 kernels) ============================

#define PAD 8
__global__ __launch_bounds__(256) void k_gateup_fb(
    const __bf16* __restrict__ xbf, const float* __restrict__ gw,
    const float* __restrict__ uw, const int* __restrict__ row_token,
    const int* __restrict__ offsets, __bf16* __restrict__ abuf) {
  int e = blockIdx.z;
  int row_start = offsets[e], row_end = offsets[e + 1];
  int tile_row = row_start + blockIdx.y * 128;
  if (tile_row >= row_end) return;
  int n0 = blockIdx.x * 128;

  __shared__ __align__(16) __bf16 As[128][BK + PAD];
  __shared__ __align__(16) __bf16 Bgs[128][BK + PAD];
  __shared__ __align__(16) __bf16 Bus[128][BK + PAD];
  __shared__ int toks[128];

  int tid = threadIdx.x;
  if (tid < 128) {
    int r = tile_row + tid;
    toks[tid] = (r < row_end) ? row_token[r] : row_token[row_start];
  }
  __syncthreads();

  f32x4 accg[4][4]; f32x4 accu[4][4];
#pragma unroll
  for (int i = 0; i < 4; ++i)
#pragma unroll
    for (int j = 0; j < 4; ++j) { accg[i][j] = (f32x4)0.f; accu[i][j] = (f32x4)0.f; }

  int wid = tid >> 6, lane = tid & 63;
  int wm = (wid >> 1) * 64, wn = (wid & 1) * 64;
  int lr = lane & 15, lk = (lane >> 4) * 8;

  const float* gbase = gw + (size_t)e * DIM * FE + n0;
  const float* ubase = uw + (size_t)e * DIM * FE + n0;
  int n4 = (tid & 31) * 4;
  int kb = tid >> 5;

  for (int k0 = 0; k0 < DIM; k0 += BK) {
#pragma unroll
    for (int p = 0; p < 2; ++p) {
      int g = tid + p * 256;
      int r = g >> 2, kk = (g & 3) * 8;
      *(bf16x8*)&As[r][kk] = *(const bf16x8*)(xbf + (size_t)toks[r] * DIM + k0 + kk);
    }
#pragma unroll
    for (int p = 0; p < 4; ++p) {
      int k = kb + p * 8;
      const float4 vg = *(const float4*)(gbase + (size_t)(k0 + k) * FE + n4);
      const float4 vu = *(const float4*)(ubase + (size_t)(k0 + k) * FE + n4);
      Bgs[n4 + 0][k] = (__bf16)vg.x; Bgs[n4 + 1][k] = (__bf16)vg.y;
      Bgs[n4 + 2][k] = (__bf16)vg.z; Bgs[n4 + 3][k] = (__bf16)vg.w;
      Bus[n4 + 0][k] = (__bf16)vu.x; Bus[n4 + 1][k] = (__bf16)vu.y;
      Bus[n4 + 2][k] = (__bf16)vu.z; Bus[n4 + 3][k] = (__bf16)vu.w;
    }
    __syncthreads();

    bf16x8 af[4];
#pragma unroll
    for (int mi = 0; mi < 4; ++mi)
      af[mi] = *(const bf16x8*)&As[wm + mi * 16 + lr][lk];
#pragma unroll
    for (int ni = 0; ni < 4; ++ni) {
      bf16x8 bg = *(const bf16x8*)&Bgs[wn + ni * 16 + lr][lk];
      bf16x8 bu = *(const bf16x8*)&Bus[wn + ni * 16 + lr][lk];
#pragma unroll
      for (int mi = 0; mi < 4; ++mi) {
        accg[mi][ni] = MFMA16(af[mi], bg, accg[mi][ni]);
        accu[mi][ni] = MFMA16(af[mi], bu, accu[mi][ni]);
      }
    }
    __syncthreads();
  }

  int rowq = (lane >> 4) * 4;
#pragma unroll
  for (int mi = 0; mi < 4; ++mi) {
#pragma unroll
    for (int ni = 0; ni < 4; ++ni) {
#pragma unroll
      for (int j = 0; j < 4; ++j) {
        int rg = tile_row + wm + mi * 16 + rowq + j;
        if (rg < row_end) {
          float g = accg[mi][ni][j], u = accu[mi][ni][j];
          float sig = 1.f / (1.f + __expf(-g));
          abuf[(size_t)rg * FE + n0 + wn + ni * 16 + lr] = (__bf16)(g * sig * u);
        }
      }
    }
  }
}

__global__ __launch_bounds__(256) void k_down_fb(
    const __bf16* __restrict__ abuf, const float* __restrict__ dw,
    const int* __restrict__ row_token, const float* __restrict__ row_wt,
    const int* __restrict__ offsets, float* __restrict__ out) {
  int e = blockIdx.z;
  int row_start = offsets[e], row_end = offsets[e + 1];
  int tile_row = row_start + blockIdx.y * 128;
  if (tile_row >= row_end) return;
  int n0 = blockIdx.x * 128;

  __shared__ __align__(16) __bf16 As[128][BK + PAD];
  __shared__ __align__(16) __bf16 Bs[128][BK + PAD];

  int tid = threadIdx.x;
  f32x4 acc[4][4];
#pragma unroll
  for (int i = 0; i < 4; ++i)
#pragma unroll
    for (int j = 0; j < 4; ++j) acc[i][j] = (f32x4)0.f;

  int wid = tid >> 6, lane = tid & 63;
  int wm = (wid >> 1) * 64, wn = (wid & 1) * 64;
  int lr = lane & 15, lk = (lane >> 4) * 8;

  const float* dbase = dw + (size_t)e * FE * DIM + n0;
  int n4 = (tid & 31) * 4;
  int kb = tid >> 5;

  for (int k0 = 0; k0 < FE; k0 += BK) {
#pragma unroll
    for (int p = 0; p < 2; ++p) {
      int g = tid + p * 256;
      int r = g >> 2, kk = (g & 3) * 8;
      *(bf16x8*)&As[r][kk] = *(const bf16x8*)(abuf + (size_t)(tile_row + r) * FE + k0 + kk);
    }
#pragma unroll
    for (int p = 0; p < 4; ++p) {
      int k = kb + p * 8;
      const float4 vb = *(const float4*)(dbase + (size_t)(k0 + k) * DIM + n4);
      Bs[n4 + 0][k] = (__bf16)vb.x; Bs[n4 + 1][k] = (__bf16)vb.y;
      Bs[n4 + 2][k] = (__bf16)vb.z; Bs[n4 + 3][k] = (__bf16)vb.w;
    }
    __syncthreads();

    bf16x8 af[4];
#pragma unroll
    for (int mi = 0; mi < 4; ++mi)
      af[mi] = *(const bf16x8*)&As[wm + mi * 16 + lr][lk];
#pragma unroll
    for (int ni = 0; ni < 4; ++ni) {
      bf16x8 bb = *(const bf16x8*)&Bs[wn + ni * 16 + lr][lk];
#pragma unroll
      for (int mi = 0; mi < 4; ++mi)
        acc[mi][ni] = MFMA16(af[mi], bb, acc[mi][ni]);
    }
    __syncthreads();
  }

  int rowq = (lane >> 4) * 4;
#pragma unroll
  for (int mi = 0; mi < 4; ++mi) {
#pragma unroll
    for (int j = 0; j < 4; ++j) {
      int rg = tile_row + wm + mi * 16 + rowq + j;
      if (rg < row_end) {
        int tok = row_token[rg];
        float w = row_wt[rg];
#pragma unroll
        for (int ni = 0; ni < 4; ++ni) {
          atomicAdd(&out[(size_t)tok * DIM + n0 + wn + ni * 16 + lr],
                    acc[mi][ni][j] * w);
        }
      }
    }
  }
}

extern "C" void kernel_launch(void* const* d_in, const int* in_sizes, int n_in,
                              void* d_out, int out_size, void* d_ws, size_t ws_size,
                              hipStream_t stream) {
  const float* x  = (const float*)d_in[0];
  const float* rw = (const float*)d_in[1];
  const float* nw = (const float*)d_in[2];
  const float* gw = (const float*)d_in[3];
  const float* uw = (const float*)d_in[4];
  const float* dwp= (const float*)d_in[5];
  float* out = (float*)d_out;

  char* p = (char*)d_ws;
  int* counts    = (int*)p;
  int* cursor    = (int*)(p + 32);
  int* offsets   = (int*)(p + 64);
  int* topi      = (int*)(p + 256);
  float* topw    = (float*)(p + 256 + 32768);
  int* row_token = (int*)(p + 256 + 65536);
  float* row_wt  = (float*)(p + 256 + 98304);
  int* invp      = (int*)(p + 256 + 131072);
  __bf16* xbf    = (__bf16*)(p + 256 + 163840);
  __bf16* abuf   = xbf + (size_t)TOK * DIM;
  __bf16* gwt    = abuf + ((size_t)2 * TOK + 128) * FE;
  __bf16* uwt    = gwt + (size_t)NE * DIM * FE;
  __bf16* dwt    = uwt + (size_t)NE * DIM * FE;
  __bf16* dbuf   = gwt;   // overlay: gwt/uwt dead after gateup

  size_t need = 256 + 163840 +
                ((size_t)TOK * DIM + ((size_t)2 * TOK + 128) * FE) * 2 +
                3 * (size_t)NE * DIM * FE * 2;
  bool fast = ws_size >= need;
  (void)cursor;

  hipMemsetAsync(p, 0, 64, stream);
  if (!fast)
    hipMemsetAsync(d_out, 0, (size_t)TOK * DIM * sizeof(float), stream);

  if (fast) {
    // router (blocks 0..4095) + weight convert (blocks 4096..10239), overlapped
    k_fused_cvt_router<<<TOK + 6144, 256, 0, stream>>>(
        x, rw, nw, xbf, topi, topw, counts, gw, uw, dwp, gwt, uwt, dwt);
    k_prefix_place<<<1, 256, 0, stream>>>(counts, offsets, topi, topw,
                                          row_token, row_wt, invp);
    k_gateup13<<<4096, 256, 0, stream>>>(xbf, gwt, uwt, row_token, offsets, abuf);
    k_down11<<<4096, 256, 0, stream>>>(abuf, dwt, offsets, dbuf);
    k_combine<<<TOK, 256, 0, stream>>>(dbuf, topw, invp, out);
  } else {
    // router only (grid = TOK -> convert blocks absent)
    k_fused_cvt_router<<<TOK, 256, 0, stream>>>(
        x, rw, nw, xbf, topi, topw, counts, gw, uw, dwp, gwt, uwt, dwt);
    k_prefix_place<<<1, 256, 0, stream>>>(counts, offsets, topi, topw,
                                          row_token, row_wt, invp);
    k_gateup_fb<<<dim3(FE / 128, 32, NE), 256, 0, stream>>>(xbf, gw, uw, row_token, offsets, abuf);
    k_down_fb<<<dim3(DIM / 128, 32, NE), 256, 0, stream>>>(abuf, dwp, row_token, row_wt, offsets, out);
  }
}